// Round 1
// baseline (238.622 us; speedup 1.0000x reference)
//
#include <hip/hip_runtime.h>

// Problem constants (match reference setup_inputs)
static constexpr int Bb = 8, Hh = 1024, Ww = 1024;
static constexpr int HW   = Hh * Ww;          // 1048576
static constexpr int NPIX = Bb * HW;          // 8388608
static constexpr int NB = 1024;               // reduction grid blocks
static constexpr int NT = 256;                // threads per block

// ---------- union-find on global labels ----------
// labels: -1 = background; otherwise parent index, parent <= node (monotone decreasing)
__device__ inline int lab_load(int* L, int i) {
    return __hip_atomic_load(&L[i], __ATOMIC_RELAXED, __HIP_MEMORY_SCOPE_AGENT);
}

__device__ inline int find_root(int* L, int x) {
    int p = lab_load(L, x);
    while (p != x) { x = p; p = lab_load(L, x); }
    return x;
}

__device__ inline void union_labels(int* L, int a, int b) {
    while (true) {
        a = find_root(L, a);
        b = find_root(L, b);
        if (a == b) return;
        if (a < b) { int t = a; a = b; b = t; }   // a > b: link a -> b
        int old = atomicMin(&L[a], b);
        if (old == a) return;                      // a was root; linked
        a = old;                                   // raced; retry from a's old parent
    }
}

// ---------- block reduction (double) ----------
__device__ inline double block_reduce(double v, double* lds) {
    for (int o = 32; o > 0; o >>= 1) v += __shfl_down(v, o, 64);
    int wave = threadIdx.x >> 6, lane = threadIdx.x & 63;
    __syncthreads();                 // protect lds across repeated calls
    if (lane == 0) lds[wave] = v;
    __syncthreads();
    double r = 0.0;
    if (threadIdx.x == 0)
        for (int w = 0; w < (int)(blockDim.x >> 6); ++w) r += lds[w];
    return r;                        // valid on thread 0
}

// ---------- K0: sums for dice/focal/tversky + label & area init ----------
__global__ void k_init(const float* __restrict__ pred, const float* __restrict__ targ,
                       int* __restrict__ lab, int* __restrict__ area,
                       double* __restrict__ part) {
    __shared__ double lds[NT / 64];
    double s_p = 0, s_t = 0, s_pt = 0, s_f = 0;
    int stride = gridDim.x * blockDim.x;
    for (int i = blockIdx.x * blockDim.x + threadIdx.x; i < NPIX; i += stride) {
        float x = pred[i];
        float t = targ[i];
        float p = 1.0f / (1.0f + expf(-x));
        float bce = fmaxf(x, 0.0f) - x * t + log1pf(expf(-fabsf(x)));
        bool pos = t > 0.5f;                 // targets are exactly 0.0 / 1.0
        float p_t = pos ? p : 1.0f - p;
        float a_t = pos ? 0.7f : 0.3f;
        float q = 1.0f - p_t;
        float q2 = q * q;
        s_p  += (double)p;
        s_t  += (double)t;
        s_pt += (double)(p * t);
        s_f  += (double)(a_t * q2 * q2 * bce);
        lab[i]  = pos ? i : -1;
        area[i] = 0;
    }
    double r;
    r = block_reduce(s_p,  lds); if (threadIdx.x == 0) part[0 * NB + blockIdx.x] = r;
    r = block_reduce(s_t,  lds); if (threadIdx.x == 0) part[1 * NB + blockIdx.x] = r;
    r = block_reduce(s_pt, lds); if (threadIdx.x == 0) part[2 * NB + blockIdx.x] = r;
    r = block_reduce(s_f,  lds); if (threadIdx.x == 0) part[3 * NB + blockIdx.x] = r;
}

// ---------- K1: union-find merge (8-connectivity, causal half-neighborhood) ----------
__global__ void k_merge(int* __restrict__ lab) {
    int stride = gridDim.x * blockDim.x;
    for (int i = blockIdx.x * blockDim.x + threadIdx.x; i < NPIX; i += stride) {
        if (lab[i] < 0) continue;
        int pix = i & (HW - 1);
        int y = pix >> 10;             // W == 1024
        int x = pix & (Ww - 1);
        if (x > 0 && lab[i - 1] >= 0)                union_labels(lab, i, i - 1);
        if (y > 0) {
            if (lab[i - Ww] >= 0)                    union_labels(lab, i, i - Ww);
            if (x > 0      && lab[i - Ww - 1] >= 0)  union_labels(lab, i, i - Ww - 1);
            if (x < Ww - 1 && lab[i - Ww + 1] >= 0)  union_labels(lab, i, i - Ww + 1);
        }
    }
}

// ---------- K2: path compression + component area count ----------
__global__ void k_compress_area(int* __restrict__ lab, int* __restrict__ area) {
    int stride = gridDim.x * blockDim.x;
    for (int i = blockIdx.x * blockDim.x + threadIdx.x; i < NPIX; i += stride) {
        if (lab[i] < 0) continue;
        int r = find_root(lab, i);
        lab[i] = r;
        atomicAdd(&area[r], 1);
    }
}

// ---------- K3: weighted BCE sum ----------
__global__ void k_wsum(const float* __restrict__ pred, const float* __restrict__ targ,
                       const int* __restrict__ lab, const int* __restrict__ area,
                       double* __restrict__ part) {
    __shared__ double lds[NT / 64];
    double s = 0;
    int stride = gridDim.x * blockDim.x;
    for (int i = blockIdx.x * blockDim.x + threadIdx.x; i < NPIX; i += stride) {
        float x = pred[i], t = targ[i];
        float bce = fmaxf(x, 0.0f) - x * t + log1pf(expf(-fabsf(x)));
        float w = 1.0f;
        int l = lab[i];
        if (l >= 0 && area[l] < 100) w = 10.0f;   // AREA_THRESH
        s += (double)(w * bce);
    }
    double r = block_reduce(s, lds);
    if (threadIdx.x == 0) part[blockIdx.x] = r;
}

// ---------- K4: final scalar ----------
__global__ void k_final(const double* __restrict__ part, float* __restrict__ out) {
    __shared__ double lds[NT / 64];
    double s[5] = {0, 0, 0, 0, 0};
    for (int j = threadIdx.x; j < NB; j += blockDim.x)
        for (int k = 0; k < 5; ++k) s[k] += part[k * NB + j];
    double red[5];
    for (int k = 0; k < 5; ++k) red[k] = block_reduce(s[k], lds);
    if (threadIdx.x == 0) {
        double sum_p = red[0], sum_t = red[1], inter = red[2];
        double sum_f = red[3], sum_w = red[4];
        double N = (double)NPIX;
        double dice    = 1.0 - (2.0 * inter + 1e-5) / (sum_p + sum_t + 1e-5);
        double focal   = sum_f / N;
        double FP = sum_p - inter, FN = sum_t - inter;
        double tversky = 1.0 - (inter + 1e-5) / (inter + 0.7 * FP + 0.3 * FN + 1e-5);
        double small   = sum_w / N;
        out[0] = (float)((dice + focal + tversky + small) * 0.25);
    }
}

extern "C" void kernel_launch(void* const* d_in, const int* in_sizes, int n_in,
                              void* d_out, int out_size, void* d_ws, size_t ws_size,
                              hipStream_t stream) {
    const float* pred = (const float*)d_in[0];
    const float* targ = (const float*)d_in[1];
    float* out = (float*)d_out;

    char* ws = (char*)d_ws;
    // layout: 5*NB doubles of partials | NPIX int labels | NPIX int areas
    double* part = (double*)ws;
    int* lab  = (int*)(ws + (size_t)5 * NB * sizeof(double));
    int* area = lab + NPIX;

    k_init<<<NB, NT, 0, stream>>>(pred, targ, lab, area, part);
    k_merge<<<4096, NT, 0, stream>>>(lab);
    k_compress_area<<<4096, NT, 0, stream>>>(lab, area);
    k_wsum<<<NB, NT, 0, stream>>>(pred, targ, lab, area, part + 4 * NB);
    k_final<<<1, NT, 0, stream>>>(part, out);
}

// Round 2
// 206.455 us; speedup vs baseline: 1.1558x; 1.1558x over previous
//
#include <hip/hip_runtime.h>

// Problem constants (match reference setup_inputs)
static constexpr int Bb = 8, Hh = 1024, Ww = 1024;
static constexpr int HW   = Hh * Ww;          // 1048576 (per-image pixels)
static constexpr int NPIX = Bb * HW;          // 8388608
static constexpr int NQ   = NPIX / 4;         // int4/float4 quads
static constexpr int NBK  = 2048;             // grid blocks (8192 waves = 100% slots)
static constexpr int NT   = 256;

// ---------- union-find on global labels ----------
// labels: -1 = background; else parent index with parent <= node (monotone decreasing)
__device__ inline int lab_load(int* L, int i) {
    return __hip_atomic_load(&L[i], __ATOMIC_RELAXED, __HIP_MEMORY_SCOPE_AGENT);
}
__device__ inline void lab_store(int* L, int i, int v) {
    __hip_atomic_store(&L[i], v, __ATOMIC_RELAXED, __HIP_MEMORY_SCOPE_AGENT);
}
__device__ inline int find_root(int* L, int x) {
    int p = lab_load(L, x);
    while (p != x) { x = p; p = lab_load(L, x); }
    return x;
}
__device__ inline void union_labels(int* L, int a, int b) {
    while (true) {
        a = find_root(L, a);
        b = find_root(L, b);
        if (a == b) return;
        if (a < b) { int t = a; a = b; b = t; }   // a > b: link a -> b
        int old = atomicMin(&L[a], b);
        if (old == a) return;                      // a was root; linked
        a = old;                                   // raced; retry from old parent
    }
}

// ---------- block reduction (double), result valid on thread 0 ----------
__device__ inline double block_reduce(double v, double* lds) {
    for (int o = 32; o > 0; o >>= 1) v += __shfl_down(v, o, 64);
    int wave = threadIdx.x >> 6, lane = threadIdx.x & 63;
    __syncthreads();
    if (lane == 0) lds[wave] = v;
    __syncthreads();
    double r = 0.0;
    if (threadIdx.x == 0)
        for (int w = 0; w < (int)(blockDim.x >> 6); ++w) r += lds[w];
    return r;
}

// cheap stable bce: max(x,0) - x*t + log1p(exp(-|x|)), e passed in = exp(-|x|)
__device__ inline float bce_from(float x, float t, float e) {
    return fmaxf(x, 0.0f) - x * t + __logf(1.0f + e);
}

// ---------- K0: global sums (p, t, p*t, focal, bce) + label init ----------
__global__ void k_init(const float4* __restrict__ pred4, const float4* __restrict__ targ4,
                       int4* __restrict__ lab4, double* __restrict__ part) {
    __shared__ double lds[NT / 64];
    float s_p = 0.f, s_t = 0.f, s_pt = 0.f, s_f = 0.f, s_b = 0.f;
    int tid = blockIdx.x * blockDim.x + threadIdx.x;
    int stride = gridDim.x * blockDim.x;
    for (int q = tid; q < NQ; q += stride) {
        float4 xv = pred4[q];
        float4 tv = targ4[q];
        int4 lv;
        int base = q << 2;
        const float* xa = &xv.x;
        const float* ta = &tv.x;
        int* la = &lv.x;
        #pragma unroll
        for (int e = 0; e < 4; ++e) {
            float x = xa[e], t = ta[e];
            float ax = fabsf(x);
            float ee = __expf(-ax);
            float rin = __builtin_amdgcn_rcpf(1.0f + ee);   // 1/(1+e)
            float p = (x >= 0.0f) ? rin : 1.0f - rin;       // sigmoid(x)
            float bce = bce_from(x, t, ee);
            bool pos = t > 0.5f;                            // targets are exact 0/1
            float q1 = pos ? (1.0f - p) : p;                // 1 - p_t
            float at = pos ? 0.7f : 0.3f;
            float q2 = q1 * q1;
            s_p  += p;
            s_t  += t;
            s_pt += pos ? p : 0.0f;
            s_f  += at * q2 * q2 * bce;
            s_b  += bce;
            la[e] = pos ? (base + e) : -1;
        }
        lab4[q] = lv;
    }
    double r;
    r = block_reduce((double)s_p,  lds); if (threadIdx.x == 0) part[0 * NBK + blockIdx.x] = r;
    r = block_reduce((double)s_t,  lds); if (threadIdx.x == 0) part[1 * NBK + blockIdx.x] = r;
    r = block_reduce((double)s_pt, lds); if (threadIdx.x == 0) part[2 * NBK + blockIdx.x] = r;
    r = block_reduce((double)s_f,  lds); if (threadIdx.x == 0) part[3 * NBK + blockIdx.x] = r;
    r = block_reduce((double)s_b,  lds); if (threadIdx.x == 0) part[4 * NBK + blockIdx.x] = r;
}

// ---------- K1: union-find merge, quad-at-a-time, 8-conn causal w/ up-shortcut ----------
__global__ void k_merge(int* __restrict__ lab) {
    const int4* lab4 = (const int4*)lab;
    int tid = blockIdx.x * blockDim.x + threadIdx.x;
    int stride = gridDim.x * blockDim.x;
    for (int q = tid; q < NQ; q += stride) {
        int4 ov = lab4[q];
        if ((ov.x & ov.y & ov.z & ov.w) < 0) continue;   // all background (all -1)
        int o[4] = {ov.x, ov.y, ov.z, ov.w};
        int i = q << 2;
        int pix = i & (HW - 1);
        int xb = pix & (Ww - 1);
        bool has_up = pix >= Ww;
        int u[4] = {-1, -1, -1, -1};
        if (has_up) {
            int4 uv = lab4[q - (Ww >> 2)];
            u[0] = uv.x; u[1] = uv.y; u[2] = uv.z; u[3] = uv.w;
        }
        #pragma unroll
        for (int e = 0; e < 4; ++e) {
            if (o[e] < 0) continue;
            int idx = i + e;
            int xe = xb + e;
            // left
            if (e > 0) { if (o[e - 1] >= 0) union_labels(lab, idx, idx - 1); }
            else if (xe > 0 && lab[idx - 1] >= 0) union_labels(lab, idx, idx - 1);
            if (has_up) {
                if (u[e] >= 0) {
                    union_labels(lab, idx, idx - Ww);   // diagonals covered via up's row
                } else {
                    // up-left
                    if (e > 0) { if (u[e - 1] >= 0) union_labels(lab, idx, idx - Ww - 1); }
                    else if (xe > 0 && lab[idx - Ww - 1] >= 0) union_labels(lab, idx, idx - Ww - 1);
                    // up-right
                    if (e < 3) { if (u[e + 1] >= 0) union_labels(lab, idx, idx - Ww + 1); }
                    else if (xe < Ww - 1 && lab[idx - Ww + 1] >= 0) union_labels(lab, idx, idx - Ww + 1);
                }
            }
        }
    }
}

// ---------- K2: path compression + component area count ----------
__global__ void k_compress_area(int* __restrict__ lab, int* __restrict__ area) {
    const int4* lab4 = (const int4*)lab;
    int tid = blockIdx.x * blockDim.x + threadIdx.x;
    int stride = gridDim.x * blockDim.x;
    for (int q = tid; q < NQ; q += stride) {
        int4 ov = lab4[q];
        if ((ov.x & ov.y & ov.z & ov.w) < 0) continue;
        int o[4] = {ov.x, ov.y, ov.z, ov.w};
        int i = q << 2;
        #pragma unroll
        for (int e = 0; e < 4; ++e) {
            if (o[e] < 0) continue;
            int r = find_root(lab, i + e);
            lab_store(lab, i + e, r);
            atomicAdd(&area[r], 1);
        }
    }
}

// ---------- K3: sum of bce over fg pixels in small components ----------
__global__ void k_smallsum(const float* __restrict__ pred, const int* __restrict__ lab,
                           const int* __restrict__ area, double* __restrict__ part) {
    __shared__ double lds[NT / 64];
    const int4* lab4 = (const int4*)lab;
    float s = 0.f;
    int tid = blockIdx.x * blockDim.x + threadIdx.x;
    int stride = gridDim.x * blockDim.x;
    for (int q = tid; q < NQ; q += stride) {
        int4 ov = lab4[q];
        if ((ov.x & ov.y & ov.z & ov.w) < 0) continue;
        int o[4] = {ov.x, ov.y, ov.z, ov.w};
        int i = q << 2;
        #pragma unroll
        for (int e = 0; e < 4; ++e) {
            int r = o[e];
            if (r < 0) continue;
            if (area[r] < 100) {                 // AREA_THRESH
                float x = pred[i + e];           // t == 1 here
                float ee = __expf(-fabsf(x));
                s += fmaxf(-x, 0.0f) + __logf(1.0f + ee);   // bce(x, t=1)
            }
        }
    }
    double r = block_reduce((double)s, lds);
    if (threadIdx.x == 0) part[5 * NBK + blockIdx.x] = r;
}

// ---------- K4: final scalar ----------
__global__ void k_final(const double* __restrict__ part, float* __restrict__ out) {
    __shared__ double lds[NT / 64];
    double s[6] = {0, 0, 0, 0, 0, 0};
    for (int j = threadIdx.x; j < NBK; j += blockDim.x)
        #pragma unroll
        for (int k = 0; k < 6; ++k) s[k] += part[k * NBK + j];
    double red[6];
    for (int k = 0; k < 6; ++k) red[k] = block_reduce(s[k], lds);
    if (threadIdx.x == 0) {
        double sum_p = red[0], sum_t = red[1], inter = red[2];
        double sum_f = red[3], sum_b = red[4], small_b = red[5];
        double N = (double)NPIX;
        double dice    = 1.0 - (2.0 * inter + 1e-5) / (sum_p + sum_t + 1e-5);
        double focal   = sum_f / N;
        double FP = sum_p - inter, FN = sum_t - inter;
        double tversky = 1.0 - (inter + 1e-5) / (inter + 0.7 * FP + 0.3 * FN + 1e-5);
        double small   = (sum_b + 9.0 * small_b) / N;
        out[0] = (float)((dice + focal + tversky + small) * 0.25);
    }
}

extern "C" void kernel_launch(void* const* d_in, const int* in_sizes, int n_in,
                              void* d_out, int out_size, void* d_ws, size_t ws_size,
                              hipStream_t stream) {
    const float* pred = (const float*)d_in[0];
    const float* targ = (const float*)d_in[1];
    float* out = (float*)d_out;

    char* ws = (char*)d_ws;
    // layout: 6*NBK doubles of partials | NPIX int labels | NPIX int areas
    double* part = (double*)ws;
    int* lab  = (int*)(ws + (size_t)6 * NBK * sizeof(double));
    int* area = lab + NPIX;

    hipMemsetAsync(area, 0, (size_t)NPIX * sizeof(int), stream);
    k_init<<<NBK, NT, 0, stream>>>((const float4*)pred, (const float4*)targ,
                                   (int4*)lab, part);
    k_merge<<<NBK, NT, 0, stream>>>(lab);
    k_compress_area<<<NBK, NT, 0, stream>>>(lab, area);
    k_smallsum<<<NBK, NT, 0, stream>>>(pred, lab, area, part);
    k_final<<<1, NT, 0, stream>>>(part, out);
}

// Round 3
// 171.549 us; speedup vs baseline: 1.3910x; 1.2035x over previous
//
#include <hip/hip_runtime.h>

// Problem constants (match reference setup_inputs)
static constexpr int Bb = 8, Hh = 1024, Ww = 1024;
static constexpr int HW    = Hh * Ww;         // 1048576 px per image
static constexpr int NPIX  = Bb * HW;         // 8388608
static constexpr int NQ    = NPIX / 4;        // float4 quads
static constexpr int NWORDS = NPIX / 64;      // 131072 mask words
static constexpr int WPR   = Ww / 64;         // 16 words per row
static constexpr int WPI   = HW / 64;         // 16384 words per image
static constexpr int NBK = 2048, NT = 256;    // init grid
static constexpr int GT  = NBK * NT;          // 524288 threads (4 quads each)
static constexpr int MBK = NWORDS / NT;       // 512 blocks for mask kernels

typedef unsigned long long u64;

// ---------- union-find (labels valid ONLY at fg pixels) ----------
__device__ inline int lab_load(int* L, int i) {
    return __hip_atomic_load(&L[i], __ATOMIC_RELAXED, __HIP_MEMORY_SCOPE_AGENT);
}
__device__ inline void lab_store(int* L, int i, int v) {
    __hip_atomic_store(&L[i], v, __ATOMIC_RELAXED, __HIP_MEMORY_SCOPE_AGENT);
}
__device__ inline int find_root(int* L, int x) {
    int p = lab_load(L, x);
    while (p != x) { x = p; p = lab_load(L, x); }
    return x;
}
__device__ inline void union_labels(int* L, int a, int b) {
    while (true) {
        a = find_root(L, a);
        b = find_root(L, b);
        if (a == b) return;
        if (a < b) { int t = a; a = b; b = t; }   // link larger -> smaller
        int old = atomicMin(&L[a], b);
        if (old == a) return;
        a = old;
    }
}

// ---------- block reduction (double), valid on thread 0 ----------
__device__ inline double block_reduce(double v, double* lds) {
    for (int o = 32; o > 0; o >>= 1) v += __shfl_down(v, o, 64);
    int wave = threadIdx.x >> 6, lane = threadIdx.x & 63;
    __syncthreads();
    if (lane == 0) lds[wave] = v;
    __syncthreads();
    double r = 0.0;
    if (threadIdx.x == 0)
        for (int w = 0; w < (int)(blockDim.x >> 6); ++w) r += lds[w];
    return r;
}

// bce at a fg pixel (t == 1): softplus(-x) = max(-x,0) + log1p(exp(-|x|))
__device__ inline float bce_pos(float x) {
    return fmaxf(-x, 0.0f) + __logf(1.0f + __expf(-fabsf(x)));
}

// ---------- K0: sums (p,t,pt,focal,bce) + mask build + sparse lab/area init ----
__global__ void k_init(const float4* __restrict__ pred4, const float4* __restrict__ targ4,
                       u64* __restrict__ mask, int* __restrict__ lab,
                       int* __restrict__ area, double* __restrict__ part) {
    __shared__ unsigned int nib[NT];
    __shared__ double lds[NT / 64];
    float s_p = 0.f, s_t = 0.f, s_pt = 0.f, s_f = 0.f, s_b = 0.f;
    #pragma unroll
    for (int pass = 0; pass < 4; ++pass) {
        int q = pass * GT + blockIdx.x * NT + threadIdx.x;   // exact: 4*GT == NQ
        float4 xv = pred4[q];
        float4 tv = targ4[q];
        const float* xa = &xv.x;
        const float* ta = &tv.x;
        unsigned int nb = 0;
        int base = q << 2;
        #pragma unroll
        for (int e = 0; e < 4; ++e) {
            float x = xa[e], t = ta[e];
            float ax = fabsf(x);
            float ee = __expf(-ax);
            float rin = __builtin_amdgcn_rcpf(1.0f + ee);    // sigmoid(|x|)
            float p = (x >= 0.0f) ? rin : 1.0f - rin;
            float bce = fmaxf(x, 0.0f) - x * t + __logf(1.0f + ee);
            bool pos = t > 0.5f;                             // targets exact 0/1
            float q1 = pos ? (1.0f - p) : p;                 // 1 - p_t
            float at = pos ? 0.7f : 0.3f;
            float q2 = q1 * q1;
            s_p  += p;
            s_t  += t;
            s_pt += pos ? p : 0.0f;
            s_f  += at * q2 * q2 * bce;
            s_b  += bce;
            if (pos) {
                nb |= 1u << e;
                lab[base + e]  = base + e;
                area[base + e] = 0;
            }
        }
        nib[threadIdx.x] = nb;
        __syncthreads();
        if ((threadIdx.x & 15) == 0) {
            u64 w = 0;
            #pragma unroll
            for (int j = 0; j < 16; ++j)
                w |= (u64)(nib[threadIdx.x + j] & 0xFu) << (4 * j);
            mask[((pass * GT + blockIdx.x * NT) >> 4) + (threadIdx.x >> 4)] = w;
        }
        __syncthreads();
    }
    double r;
    r = block_reduce((double)s_p,  lds); if (threadIdx.x == 0) part[0 * NBK + blockIdx.x] = r;
    r = block_reduce((double)s_t,  lds); if (threadIdx.x == 0) part[1 * NBK + blockIdx.x] = r;
    r = block_reduce((double)s_pt, lds); if (threadIdx.x == 0) part[2 * NBK + blockIdx.x] = r;
    r = block_reduce((double)s_f,  lds); if (threadIdx.x == 0) part[3 * NBK + blockIdx.x] = r;
    r = block_reduce((double)s_b,  lds); if (threadIdx.x == 0) part[4 * NBK + blockIdx.x] = r;
}

// neighbor masks for word wi (zero-filled at image/row boundaries)
struct Nbr { u64 L, R, U, UL, UR, D, DL, DR; };
__device__ inline Nbr neighbors(const u64* __restrict__ mask, int wi, u64 cur) {
    int y  = (wi & (WPI - 1)) >> 4;   // row within image
    int wx = wi & (WPR - 1);
    u64 lf = wx > 0       ? mask[wi - 1] : 0;
    u64 rt = wx < WPR - 1 ? mask[wi + 1] : 0;
    u64 up = 0, ul = 0, ur = 0, dn = 0, dl = 0, dr = 0;
    if (y > 0) {
        up = mask[wi - WPR];
        ul = wx > 0       ? mask[wi - WPR - 1] : 0;
        ur = wx < WPR - 1 ? mask[wi - WPR + 1] : 0;
    }
    if (y < Hh - 1) {
        dn = mask[wi + WPR];
        dl = wx > 0       ? mask[wi + WPR - 1] : 0;
        dr = wx < WPR - 1 ? mask[wi + WPR + 1] : 0;
    }
    Nbr n;
    n.L  = (cur << 1) | (lf >> 63);
    n.R  = (cur >> 1) | (rt << 63);
    n.U  = up;
    n.UL = (up << 1) | (ul >> 63);
    n.UR = (up >> 1) | (ur << 63);
    n.D  = dn;
    n.DL = (dn << 1) | (dl >> 63);
    n.DR = (dn >> 1) | (dr << 63);
    return n;
}

// ---------- K1: unions (causal) + isolated-pixel bce sum ----------
__global__ void k_merge(const u64* __restrict__ mask, int* __restrict__ lab,
                        const float* __restrict__ pred, double* __restrict__ part_iso) {
    __shared__ double lds[NT / 64];
    int wi = blockIdx.x * NT + threadIdx.x;
    u64 cur = mask[wi];
    float s_iso = 0.f;
    if (cur) {
        Nbr n = neighbors(mask, wi, cur);
        u64 anyN = n.L | n.R | n.U | n.UL | n.UR | n.D | n.DL | n.DR;
        int base = wi << 6;
        u64 iso = cur & ~anyN;
        while (iso) {
            int b = __builtin_ctzll(iso); iso &= iso - 1;
            s_iso += bce_pos(pred[base + b]);
        }
        u64 work = cur & (n.L | n.U | n.UL | n.UR);
        while (work) {
            int b = __builtin_ctzll(work); work &= work - 1;
            u64 bit = 1ull << b;
            int i = base + b;
            if (n.L & bit) union_labels(lab, i, i - 1);
            if (n.U & bit) union_labels(lab, i, i - Ww);   // diagonals covered via up row
            else {
                if (n.UL & bit) union_labels(lab, i, i - Ww - 1);
                if (n.UR & bit) union_labels(lab, i, i - Ww + 1);
            }
        }
    }
    double r = block_reduce((double)s_iso, lds);
    if (threadIdx.x == 0) part_iso[blockIdx.x] = r;
}

// ---------- K2: compress + area count (non-isolated fg only) ----------
__global__ void k_area(const u64* __restrict__ mask, int* __restrict__ lab,
                       int* __restrict__ area) {
    int wi = blockIdx.x * NT + threadIdx.x;
    u64 cur = mask[wi];
    if (!cur) return;
    Nbr n = neighbors(mask, wi, cur);
    u64 ni = cur & (n.L | n.R | n.U | n.UL | n.UR | n.D | n.DL | n.DR);
    int base = wi << 6;
    while (ni) {
        int b = __builtin_ctzll(ni); ni &= ni - 1;
        int i = base + b;
        int r = find_root(lab, i);
        lab_store(lab, i, r);
        atomicAdd(&area[r], 1);
    }
}

// ---------- K3: bce sum over non-isolated fg in small components ----------
__global__ void k_small(const u64* __restrict__ mask, const int* __restrict__ lab,
                        const int* __restrict__ area, const float* __restrict__ pred,
                        double* __restrict__ part_small) {
    __shared__ double lds[NT / 64];
    int wi = blockIdx.x * NT + threadIdx.x;
    u64 cur = mask[wi];
    float s = 0.f;
    if (cur) {
        Nbr n = neighbors(mask, wi, cur);
        u64 ni = cur & (n.L | n.R | n.U | n.UL | n.UR | n.D | n.DL | n.DR);
        int base = wi << 6;
        while (ni) {
            int b = __builtin_ctzll(ni); ni &= ni - 1;
            int i = base + b;
            int r = lab[i];                  // compressed root
            if (area[r] < 100)               // AREA_THRESH
                s += bce_pos(pred[i]);
        }
    }
    double r = block_reduce((double)s, lds);
    if (threadIdx.x == 0) part_small[blockIdx.x] = r;
}

// ---------- K4: final scalar ----------
__global__ void k_final(const double* __restrict__ part, float* __restrict__ out) {
    __shared__ double lds[NT / 64];
    const double* part_iso   = part + 5 * NBK;
    const double* part_small = part_iso + MBK;
    double s[7] = {0, 0, 0, 0, 0, 0, 0};
    for (int j = threadIdx.x; j < NBK; j += blockDim.x)
        #pragma unroll
        for (int k = 0; k < 5; ++k) s[k] += part[k * NBK + j];
    for (int j = threadIdx.x; j < MBK; j += blockDim.x) {
        s[5] += part_iso[j];
        s[6] += part_small[j];
    }
    double red[7];
    for (int k = 0; k < 7; ++k) red[k] = block_reduce(s[k], lds);
    if (threadIdx.x == 0) {
        double sum_p = red[0], sum_t = red[1], inter = red[2];
        double sum_f = red[3], sum_b = red[4];
        double small_b = red[5] + red[6];
        double N = (double)NPIX;
        double dice    = 1.0 - (2.0 * inter + 1e-5) / (sum_p + sum_t + 1e-5);
        double focal   = sum_f / N;
        double FP = sum_p - inter, FN = sum_t - inter;
        double tversky = 1.0 - (inter + 1e-5) / (inter + 0.7 * FP + 0.3 * FN + 1e-5);
        double small   = (sum_b + 9.0 * small_b) / N;
        out[0] = (float)((dice + focal + tversky + small) * 0.25);
    }
}

extern "C" void kernel_launch(void* const* d_in, const int* in_sizes, int n_in,
                              void* d_out, int out_size, void* d_ws, size_t ws_size,
                              hipStream_t stream) {
    const float* pred = (const float*)d_in[0];
    const float* targ = (const float*)d_in[1];
    float* out = (float*)d_out;

    char* ws = (char*)d_ws;
    // layout: (5*NBK + 2*MBK) doubles | NWORDS u64 mask | NPIX int lab | NPIX int area
    double* part = (double*)ws;
    u64* mask = (u64*)(ws + (size_t)(5 * NBK + 2 * MBK) * sizeof(double));
    int* lab  = (int*)(mask + NWORDS);
    int* area = lab + NPIX;

    k_init<<<NBK, NT, 0, stream>>>((const float4*)pred, (const float4*)targ,
                                   mask, lab, area, part);
    k_merge<<<MBK, NT, 0, stream>>>(mask, lab, pred, part + 5 * NBK);
    k_area <<<MBK, NT, 0, stream>>>(mask, lab, area);
    k_small<<<MBK, NT, 0, stream>>>(mask, lab, area, pred, part + 5 * NBK + MBK);
    k_final<<<1, NT, 0, stream>>>(part, out);
}